// Round 12
// baseline (280.913 us; speedup 1.0000x reference)
//
#include <hip/hip_runtime.h>
#include <float.h>

#define BB 32
#define QQ 900
#define TT 300
#define CC 256

// ---------------------------------------------------------------------------
// Kernel A: per-(b,q) softmax stats: rowmax and sum(exp(l - max))
// ---------------------------------------------------------------------------
__global__ __launch_bounds__(256)
void softmax_stats_kernel(const float* __restrict__ logits, float2* __restrict__ stats)
{
    const int row = blockIdx.x;                 // b*QQ + q
    const float* L = logits + (size_t)row * CC;
    const int tid = threadIdx.x;
    float x = L[tid];

    __shared__ float sredm[4];
    __shared__ float sreds[4];

    float m = x;
    #pragma unroll
    for (int off = 32; off > 0; off >>= 1)
        m = fmaxf(m, __shfl_down(m, off, 64));
    if ((tid & 63) == 0) sredm[tid >> 6] = m;
    __syncthreads();
    m = fmaxf(fmaxf(sredm[0], sredm[1]), fmaxf(sredm[2], sredm[3]));

    float s = expf(x - m);
    #pragma unroll
    for (int off = 32; off > 0; off >>= 1)
        s += __shfl_down(s, off, 64);
    if ((tid & 63) == 0) sreds[tid >> 6] = s;
    __syncthreads();
    if (tid == 0)
        stats[row] = make_float2(m, sreds[0] + sreds[1] + sreds[2] + sreds[3]);
}

// ---------------------------------------------------------------------------
// Kernel B: cost matrix, 32q x 32t tiles. Writes Cmat [b][q][t] coalesced,
// CT [b][t][q] coalesced (LDS transpose), and the per-(b,t) row-min key via
// one u64 atomicMin per (tile, t): key = mono32(cost)<<10 | q.
// ---------------------------------------------------------------------------
__global__ __launch_bounds__(256)
void cost_kernel(const float* __restrict__ logits,
                 const float* __restrict__ pboxes,
                 const float* __restrict__ pcut,
                 const int*   __restrict__ tlabels,
                 const float* __restrict__ tboxes,
                 const float* __restrict__ tcut,
                 const float2* __restrict__ stats,
                 float* __restrict__ Cmat,
                 float* __restrict__ CT,
                 unsigned long long* __restrict__ rowkey)
{
    const int b  = blockIdx.z;
    const int q0 = blockIdx.x * 32;
    const int t0 = blockIdx.y * 32;
    const int tid = threadIdx.x;

    __shared__ float s_pb[32][4], s_tb[32][4];
    __shared__ float s_pc[32], s_tc[32], s_pm[32], s_ps[32], s_pa[32], s_ta[32];
    __shared__ int   s_tl[32];
    __shared__ float s_tile[32][33];

    if (tid < 32) {
        int q = q0 + tid;
        if (q < QQ) {
            const float* pb = pboxes + ((size_t)b * QQ + q) * 4;
            float x1 = pb[0], y1 = pb[1], x2 = pb[2], y2 = pb[3];
            s_pb[tid][0] = x1; s_pb[tid][1] = y1; s_pb[tid][2] = x2; s_pb[tid][3] = y2;
            s_pa[tid] = (x2 - x1) * (y2 - y1);
            s_pc[tid] = pcut[(size_t)b * QQ + q];
            float2 st = stats[(size_t)b * QQ + q];
            s_pm[tid] = st.x; s_ps[tid] = st.y;
        }
    } else if (tid < 64) {
        int tl = tid - 32;
        int t = t0 + tl;
        if (t < TT) {
            const float* tb = tboxes + ((size_t)b * TT + t) * 4;
            float x1 = tb[0], y1 = tb[1], x2 = tb[2], y2 = tb[3];
            s_tb[tl][0] = x1; s_tb[tl][1] = y1; s_tb[tl][2] = x2; s_tb[tl][3] = y2;
            s_ta[tl] = (x2 - x1) * (y2 - y1);
            s_tc[tl] = tcut[(size_t)b * TT + t];
            s_tl[tl] = tlabels[(size_t)b * TT + t];
        }
    }
    __syncthreads();

    const int tl = tid & 31;
    const int t  = t0 + tl;
    #pragma unroll
    for (int k = 0; k < 4; ++k) {
        int ql = (tid >> 5) + 8 * k;
        int q  = q0 + ql;
        if (q < QQ && t < TT) {
            float lg = logits[((size_t)b * QQ + q) * CC + s_tl[tl]];
            float cclass = -(expf(lg - s_pm[ql]) / s_ps[ql]);

            float px1 = s_pb[ql][0], py1 = s_pb[ql][1], px2 = s_pb[ql][2], py2 = s_pb[ql][3];
            float tx1 = s_tb[tl][0], ty1 = s_tb[tl][1], tx2 = s_tb[tl][2], ty2 = s_tb[tl][3];

            float l1 = fabsf(px1 - tx1) + fabsf(py1 - ty1) + fabsf(px2 - tx2) + fabsf(py2 - ty2);

            float iw = fmaxf(fminf(px2, tx2) - fmaxf(px1, tx1), 0.0f);
            float ih = fmaxf(fminf(py2, ty2) - fmaxf(py1, ty1), 0.0f);
            float inter = iw * ih;
            float uni = s_pa[ql] + s_ta[tl] - inter;
            float iou = inter / uni;

            float ew = fmaxf(fmaxf(px2, tx2) - fminf(px1, tx1), 0.0f);
            float eh = fmaxf(fmaxf(py2, ty2) - fminf(py1, ty1), 0.0f);
            float enc = ew * eh;
            float giou = iou - (enc - uni) / enc;

            float cost = 5.0f * l1 + cclass - 2.0f * giou
                       + 2.0f * fabsf(s_pc[ql] - s_tc[tl]);

            Cmat[((size_t)b * QQ + q) * TT + t] = cost;
            s_tile[ql][tl] = cost;
        }
    }
    __syncthreads();

    if (CT != nullptr) {
        #pragma unroll
        for (int k = 0; k < 4; ++k) {
            int tl2 = (tid >> 5) + 8 * k;
            int ql2 = tid & 31;
            int t2 = t0 + tl2, q2 = q0 + ql2;
            if (q2 < QQ && t2 < TT)
                CT[((size_t)b * TT + t2) * QQ + q2] = s_tile[ql2][tl2];
        }
    }

    // fused row-min: per t-row of this tile, min over the tile's q's
    if (tid < 32) {
        int t2 = t0 + tid;
        if (t2 < TT) {
            int qmax = (QQ - q0 < 32) ? (QQ - q0) : 32;
            unsigned long long best = ~0ull;
            for (int ql2 = 0; ql2 < qmax; ++ql2) {
                unsigned ub = __float_as_uint(s_tile[ql2][tid]);
                unsigned mono = (ub & 0x80000000u) ? ~ub : (ub | 0x80000000u);
                unsigned long long key = ((unsigned long long)mono << 10)
                                       | (unsigned)(q0 + ql2);
                if (key < best) best = key;
            }
            atomicMin(&rowkey[(size_t)b * TT + t2], best);
        }
    }
}

// ---------------------------------------------------------------------------
// Kernel C: JV LSA = greedy init (fused raw row mins, v=0) + SAP.
// Round-11 semantics EXACTLY (same keys, same tie-break, same dual math).
// New: (1) v-duals live in persistent per-thread registers (LDS v0 deleted;
// incremental updates from broadcast usedList/Dent), (2) owner array is
// 0-based pcol[] read per row as one aligned ds_read_b128, (3) speculative
// prefetch of all 4 wave-candidate rows right after the barrier (winner
// selected by key compare — keys unique since they contain j), (4) next free
// row's first float4 prefetched during the augment phase.
//   key = mono45(cur) | j:10 | owner:9     (owner = pcol[j-1], frozen/row)
// ---------------------------------------------------------------------------
#define STH 256
#define NW (STH / 64)
#define KCOLS 4
#define MLOW ((1ull << 19) - 1ull)

__device__ __forceinline__ unsigned long long monoKey(double x) {
    unsigned long long ub = (unsigned long long)__double_as_longlong(x);
    return (ub & 0x8000000000000000ull) ? ~ub : (ub | 0x8000000000000000ull);
}
__device__ __forceinline__ double unmonoKey(unsigned long long m) {
    unsigned long long ub = (m >> 63) ? (m & 0x7FFFFFFFFFFFFFFFull) : ~m;
    return __longlong_as_double((long long)ub);
}

__device__ __forceinline__ unsigned wave_min_u32(unsigned x) {
    unsigned t;
    t = (unsigned)__builtin_amdgcn_update_dpp((int)x, (int)x, 0x111, 0xf, 0xf, false); // row_shr:1
    x = (x < t) ? x : t;
    t = (unsigned)__builtin_amdgcn_update_dpp((int)x, (int)x, 0x112, 0xf, 0xf, false); // row_shr:2
    x = (x < t) ? x : t;
    t = (unsigned)__builtin_amdgcn_update_dpp((int)x, (int)x, 0x114, 0xf, 0xf, false); // row_shr:4
    x = (x < t) ? x : t;
    t = (unsigned)__builtin_amdgcn_update_dpp((int)x, (int)x, 0x118, 0xf, 0xf, false); // row_shr:8
    x = (x < t) ? x : t;
    t = (unsigned)__builtin_amdgcn_update_dpp((int)x, (int)x, 0x142, 0xa, 0xf, false); // row_bcast15
    x = (x < t) ? x : t;
    t = (unsigned)__builtin_amdgcn_update_dpp((int)x, (int)x, 0x143, 0xc, 0xf, false); // row_bcast31
    x = (x < t) ? x : t;
    return (unsigned)__builtin_amdgcn_readlane((int)x, 63);
}

__global__ __launch_bounds__(STH)
void lsa_kernel(const float* __restrict__ Mbase,
                long long batchStride, long long rowStride, long long colStride,
                const unsigned long long* __restrict__ rowkey,
                float* __restrict__ outq, float* __restrict__ outt)
{
    const int b = blockIdx.x;
    const float* M = Mbase + (size_t)b * batchStride;
    const int tid = threadIdx.x;

    __shared__ double u0[TT + 1];
    __shared__ __align__(16) int pcol[QQ];     // 0-based column owner (0 = free)
    __shared__ int    way[QQ + 1];
    __shared__ int    claim[QQ + 1];
    __shared__ int    freeRows[TT];
    __shared__ int    usedList[TT + 1];
    __shared__ double Dent[TT + 1];
    __shared__ unsigned long long redK[2][NW];
    __shared__ int    waveBase[NW];
    __shared__ int    chunkBase;

    for (int j = tid; j <= QQ; j += STH) { way[j] = 0; claim[j] = 0x7FFFFFFF; }
    for (int c = tid; c < QQ; c += STH) pcol[c] = 0;
    for (int i = tid + 1; i <= TT; i += STH) {
        unsigned long long rk = rowkey[(size_t)b * TT + i - 1];
        unsigned mono = (unsigned)(rk >> 10);
        unsigned ub = (mono & 0x80000000u) ? (mono & 0x7FFFFFFFu) : ~mono;
        u0[i] = (double)__uint_as_float(ub);     // EXACT row min (float)
    }
    if (tid == 0) chunkBase = 0;
    __syncthreads();

    // ---- greedy: earliest row claims its argmin column.
    for (int i = tid + 1; i <= TT; i += STH)
        atomicMin(&claim[(int)(rowkey[(size_t)b * TT + i - 1] & 1023ull) + 1], i);
    __syncthreads();

    // winners write pcol; losers compacted IN ORDER into freeRows
    for (int r = 0; r < (TT + STH - 1) / STH; ++r) {
        int i = tid + r * STH + 1;
        bool lose = false;
        if (i <= TT) {
            int j = (int)(rowkey[(size_t)b * TT + i - 1] & 1023ull) + 1;
            if (claim[j] == i) pcol[j - 1] = i; else lose = true;
        }
        unsigned long long mk = __ballot(lose);
        int lane = tid & 63, w = tid >> 6;
        int lanePre = __popcll(mk & ((1ull << lane) - 1ull));
        if (lane == 0) waveBase[w] = __popcll(mk);
        __syncthreads();
        if (tid == 0) {
            int acc = chunkBase;
            for (int w2 = 0; w2 < NW; ++w2) { int c = waveBase[w2]; waveBase[w2] = acc; acc += c; }
            chunkBase = acc;
        }
        __syncthreads();
        if (lose) freeRows[waveBase[w] + lanePre] = i;
        __syncthreads();
    }
    const int nFree = chunkBase;

    const int c0 = 4 * tid;                  // first owned column (0-based)
    const bool vec = (colStride == 1) && (c0 < QQ);   // full float4 in range (900%4==0)

    // persistent v duals for owned columns (v starts at 0 everywhere)
    double v0r[KCOLS] = {0.0, 0.0, 0.0, 0.0};
    bool valid[KCOLS];
    #pragma unroll
    for (int k = 0; k < KCOLS; ++k) valid[k] = (c0 + k < QQ);

    // prologue: prefetch first free row
    float4 pre4 = make_float4(0.f, 0.f, 0.f, 0.f);
    if (vec && nFree > 0)
        pre4 = *reinterpret_cast<const float4*>(M + (long long)(freeRows[0] - 1) * rowStride + c0);

    // ---- shortest augmenting path for each unassigned row.
    int par = 0;
    for (int f = 0; f < nFree; ++f) {
        const int i = freeRows[f];

        // per-row constants: owner tags (owner frozen during this Dijkstra)
        unsigned long long tag[KCOLS];
        {
            int own[KCOLS] = {0, 0, 0, 0};
            if (vec) {
                int4 pv = *reinterpret_cast<const int4*>(&pcol[c0]);   // aligned b128
                own[0] = pv.x; own[1] = pv.y; own[2] = pv.z; own[3] = pv.w;
            } else {
                #pragma unroll
                for (int k = 0; k < KCOLS; ++k)
                    if (valid[k]) own[k] = pcol[c0 + k];
            }
            #pragma unroll
            for (int k = 0; k < KCOLS; ++k)
                tag[k] = ((unsigned long long)(c0 + k + 1) << 9)
                       | (unsigned long long)own[k];
        }

        unsigned long long sv[KCOLS];
        #pragma unroll
        for (int k = 0; k < KCOLS; ++k) sv[k] = ~0ull;
        unsigned usedMask = 0;
        int cnt = 1; double D = 0.0; int i0 = i; int j0 = 0; int j1free;
        float4 cur4 = pre4;

        while (true) {
            float mload[KCOLS];
            if (vec) {
                mload[0] = cur4.x; mload[1] = cur4.y; mload[2] = cur4.z; mload[3] = cur4.w;
            } else {
                const float* Mrow = M + (long long)(i0 - 1) * rowStride;
                #pragma unroll
                for (int k = 0; k < KCOLS; ++k)
                    mload[k] = valid[k] ? Mrow[(long long)(c0 + k) * colStride] : 0.0f;
            }
            const double base = D - u0[i0];

            unsigned long long bk = ~0ull;
            #pragma unroll
            for (int k = 0; k < KCOLS; ++k) {
                if (valid[k] && !((usedMask >> k) & 1u)) {
                    double cur = (double)mload[k] + (base - v0r[k]);
                    unsigned long long key = (monoKey(cur) & ~MLOW) | tag[k];
                    if (key < sv[k]) { sv[k] = key; way[c0 + k + 1] = j0; }
                    if (sv[k] < bk) bk = sv[k];
                }
            }
            // wave-level exact u64 min via two-pass 32-bit DPP
            {
                unsigned hi = (unsigned)(bk >> 32);
                unsigned lo = (unsigned)(bk & 0xFFFFFFFFull);
                unsigned mhi = wave_min_u32(hi);
                unsigned lo2 = (hi == mhi) ? lo : 0xFFFFFFFFu;
                unsigned mlo = wave_min_u32(lo2);
                if ((tid & 63) == 0)
                    redK[par][tid >> 6] = ((unsigned long long)mhi << 32) | mlo;
            }
            __syncthreads();                       // the ONLY per-iteration barrier

            unsigned long long k0 = redK[par][0], k1 = redK[par][1];
            unsigned long long k2 = redK[par][2], k3 = redK[par][3];

            // speculative prefetch of all 4 candidate rows (keys unique -> one wins)
            float4 p0, p1, p2, p3;
            if (vec) {
                int r0 = (int)(k0 & 511ull), r1 = (int)(k1 & 511ull);
                int r2 = (int)(k2 & 511ull), r3 = (int)(k3 & 511ull);
                r0 = (r0 > 0) ? r0 - 1 : 0;  r1 = (r1 > 0) ? r1 - 1 : 0;
                r2 = (r2 > 0) ? r2 - 1 : 0;  r3 = (r3 > 0) ? r3 - 1 : 0;
                p0 = *reinterpret_cast<const float4*>(M + (long long)r0 * rowStride + c0);
                p1 = *reinterpret_cast<const float4*>(M + (long long)r1 * rowStride + c0);
                p2 = *reinterpret_cast<const float4*>(M + (long long)r2 * rowStride + c0);
                p3 = *reinterpret_cast<const float4*>(M + (long long)r3 * rowStride + c0);
            }

            unsigned long long kmin = k0;
            if (k1 < kmin) kmin = k1;
            if (k2 < kmin) kmin = k2;
            if (k3 < kmin) kmin = k3;
            par ^= 1;

            D = unmonoKey(kmin & ~MLOW);
            int j1 = (int)((kmin >> 9) & 1023ull);
            int i1 = (int)(kmin & 511ull);         // owner from the key
            if (i1 == 0) { j1free = j1; break; }   // free column reached

            if (vec)
                cur4 = (kmin == k0) ? p0 : (kmin == k1) ? p1 : (kmin == k2) ? p2 : p3;

            int cj = j1 - 1;
            if ((cj >> 2) == tid) usedMask |= 1u << (cj & 3);
            if (tid == 0) { usedList[cnt] = j1; Dent[cnt] = D; }
            cnt++;
            j0 = j1; i0 = i1;
        }

        // prefetch next free row's first float4 (hides under the epilogue)
        if (vec && f + 1 < nFree)
            pre4 = *reinterpret_cast<const float4*>(
                M + (long long)(freeRows[f + 1] - 1) * rowStride + c0);

        __syncthreads();   // A: way/usedList/Dent visible, scans done

        // register v-dual updates (all threads, broadcast reads — conflict-free)
        for (int k = 1; k < cnt; ++k) {
            int ju = usedList[k];
            double d = D - Dent[k];
            int rel = ju - 1 - c0;
            if (rel >= 0 && rel < KCOLS) v0r[rel] -= d;
        }
        // u-dual updates (reads PRE-augment pcol; rows distinct)
        for (int k = tid; k < cnt; k += STH) {
            if (k == 0) {
                u0[i] += D;
            } else {
                int ju = usedList[k];
                u0[pcol[ju - 1]] += D - Dent[k];
            }
        }
        __syncthreads();   // B

        if (tid == 0) {
            int jj = j1free;
            while (jj) {
                int jn = way[jj];
                pcol[jj - 1] = (jn == 0) ? i : pcol[jn - 1];
                jj = jn;
            }
        }
        __syncthreads();   // C: augmented pcol visible
    }

    // row2col: pcol[c] > 0 -> target pcol[c]-1 assigned query c
    for (int c = tid; c < QQ; c += STH) {
        int pi = pcol[c];
        if (pi > 0) outq[(size_t)b * TT + (pi - 1)] = (float)c;
    }
    for (int t = tid; t < TT; t += STH)
        outt[(size_t)b * TT + t] = (float)t;
}

// ---------------------------------------------------------------------------
extern "C" void kernel_launch(void* const* d_in, const int* in_sizes, int n_in,
                              void* d_out, int out_size, void* d_ws, size_t ws_size,
                              hipStream_t stream)
{
    const float* logits  = (const float*)d_in[0];
    const float* pboxes  = (const float*)d_in[1];
    const float* pcut    = (const float*)d_in[2];
    const int*   tlabels = (const int*)d_in[3];
    const float* tboxes  = (const float*)d_in[4];
    const float* tcut    = (const float*)d_in[5];

    float* out  = (float*)d_out;
    float* Cmat = out;                                   // B*Q*T
    float* outq = out + (size_t)BB * QQ * TT;            // B*T
    float* outt = outq + (size_t)BB * TT;                // B*T

    const size_t statsBytes = (size_t)BB * QQ * sizeof(float2);              // 230,400
    const size_t rkBytes    = (size_t)BB * TT * sizeof(unsigned long long);  // 76,800
    const size_t ctBytes    = (size_t)BB * TT * QQ * sizeof(float);          // 34.56 MB

    float2* stats = (float2*)d_ws;
    unsigned long long* rowkey = (unsigned long long*)((char*)d_ws + statsBytes);
    char*   ctPtr = (char*)d_ws + statsBytes + rkBytes;
    bool haveCT = (ws_size >= statsBytes + rkBytes + ctBytes);
    float* CT = haveCT ? (float*)ctPtr : nullptr;

    hipMemsetAsync(rowkey, 0xFF, rkBytes, stream);

    softmax_stats_kernel<<<BB * QQ, 256, 0, stream>>>(logits, stats);

    dim3 grid((QQ + 31) / 32, (TT + 31) / 32, BB);
    cost_kernel<<<grid, 256, 0, stream>>>(logits, pboxes, pcut, tlabels, tboxes,
                                          tcut, stats, Cmat, CT, rowkey);

    if (haveCT) {
        lsa_kernel<<<BB, STH, 0, stream>>>(
            CT, (long long)TT * QQ, (long long)QQ, 1LL, rowkey, outq, outt);
    } else {
        lsa_kernel<<<BB, STH, 0, stream>>>(
            Cmat, (long long)QQ * TT, 1LL, (long long)TT, rowkey, outq, outt);
    }
}

// Round 13
// 267.329 us; speedup vs baseline: 1.0508x; 1.0508x over previous
//
#include <hip/hip_runtime.h>
#include <float.h>

#define BB 32
#define QQ 900
#define TT 300
#define CC 256

// ---------------------------------------------------------------------------
// Kernel A: per-(b,q) softmax stats: rowmax and sum(exp(l - max))
// ---------------------------------------------------------------------------
__global__ __launch_bounds__(256)
void softmax_stats_kernel(const float* __restrict__ logits, float2* __restrict__ stats)
{
    const int row = blockIdx.x;                 // b*QQ + q
    const float* L = logits + (size_t)row * CC;
    const int tid = threadIdx.x;
    float x = L[tid];

    __shared__ float sredm[4];
    __shared__ float sreds[4];

    float m = x;
    #pragma unroll
    for (int off = 32; off > 0; off >>= 1)
        m = fmaxf(m, __shfl_down(m, off, 64));
    if ((tid & 63) == 0) sredm[tid >> 6] = m;
    __syncthreads();
    m = fmaxf(fmaxf(sredm[0], sredm[1]), fmaxf(sredm[2], sredm[3]));

    float s = expf(x - m);
    #pragma unroll
    for (int off = 32; off > 0; off >>= 1)
        s += __shfl_down(s, off, 64);
    if ((tid & 63) == 0) sreds[tid >> 6] = s;
    __syncthreads();
    if (tid == 0)
        stats[row] = make_float2(m, sreds[0] + sreds[1] + sreds[2] + sreds[3]);
}

// ---------------------------------------------------------------------------
// Kernel B: cost matrix, 32q x 32t tiles. Writes Cmat [b][q][t] coalesced,
// CT [b][t][q] coalesced (LDS transpose), and the per-(b,t) row-min key via
// one u64 atomicMin per (tile, t): key = mono32(cost)<<10 | q.
// ---------------------------------------------------------------------------
__global__ __launch_bounds__(256)
void cost_kernel(const float* __restrict__ logits,
                 const float* __restrict__ pboxes,
                 const float* __restrict__ pcut,
                 const int*   __restrict__ tlabels,
                 const float* __restrict__ tboxes,
                 const float* __restrict__ tcut,
                 const float2* __restrict__ stats,
                 float* __restrict__ Cmat,
                 float* __restrict__ CT,
                 unsigned long long* __restrict__ rowkey)
{
    const int b  = blockIdx.z;
    const int q0 = blockIdx.x * 32;
    const int t0 = blockIdx.y * 32;
    const int tid = threadIdx.x;

    __shared__ float s_pb[32][4], s_tb[32][4];
    __shared__ float s_pc[32], s_tc[32], s_pm[32], s_ps[32], s_pa[32], s_ta[32];
    __shared__ int   s_tl[32];
    __shared__ float s_tile[32][33];

    if (tid < 32) {
        int q = q0 + tid;
        if (q < QQ) {
            const float* pb = pboxes + ((size_t)b * QQ + q) * 4;
            float x1 = pb[0], y1 = pb[1], x2 = pb[2], y2 = pb[3];
            s_pb[tid][0] = x1; s_pb[tid][1] = y1; s_pb[tid][2] = x2; s_pb[tid][3] = y2;
            s_pa[tid] = (x2 - x1) * (y2 - y1);
            s_pc[tid] = pcut[(size_t)b * QQ + q];
            float2 st = stats[(size_t)b * QQ + q];
            s_pm[tid] = st.x; s_ps[tid] = st.y;
        }
    } else if (tid < 64) {
        int tl = tid - 32;
        int t = t0 + tl;
        if (t < TT) {
            const float* tb = tboxes + ((size_t)b * TT + t) * 4;
            float x1 = tb[0], y1 = tb[1], x2 = tb[2], y2 = tb[3];
            s_tb[tl][0] = x1; s_tb[tl][1] = y1; s_tb[tl][2] = x2; s_tb[tl][3] = y2;
            s_ta[tl] = (x2 - x1) * (y2 - y1);
            s_tc[tl] = tcut[(size_t)b * TT + t];
            s_tl[tl] = tlabels[(size_t)b * TT + t];
        }
    }
    __syncthreads();

    const int tl = tid & 31;
    const int t  = t0 + tl;
    #pragma unroll
    for (int k = 0; k < 4; ++k) {
        int ql = (tid >> 5) + 8 * k;
        int q  = q0 + ql;
        if (q < QQ && t < TT) {
            float lg = logits[((size_t)b * QQ + q) * CC + s_tl[tl]];
            float cclass = -(expf(lg - s_pm[ql]) / s_ps[ql]);

            float px1 = s_pb[ql][0], py1 = s_pb[ql][1], px2 = s_pb[ql][2], py2 = s_pb[ql][3];
            float tx1 = s_tb[tl][0], ty1 = s_tb[tl][1], tx2 = s_tb[tl][2], ty2 = s_tb[tl][3];

            float l1 = fabsf(px1 - tx1) + fabsf(py1 - ty1) + fabsf(px2 - tx2) + fabsf(py2 - ty2);

            float iw = fmaxf(fminf(px2, tx2) - fmaxf(px1, tx1), 0.0f);
            float ih = fmaxf(fminf(py2, ty2) - fmaxf(py1, ty1), 0.0f);
            float inter = iw * ih;
            float uni = s_pa[ql] + s_ta[tl] - inter;
            float iou = inter / uni;

            float ew = fmaxf(fmaxf(px2, tx2) - fminf(px1, tx1), 0.0f);
            float eh = fmaxf(fmaxf(py2, ty2) - fminf(py1, ty1), 0.0f);
            float enc = ew * eh;
            float giou = iou - (enc - uni) / enc;

            float cost = 5.0f * l1 + cclass - 2.0f * giou
                       + 2.0f * fabsf(s_pc[ql] - s_tc[tl]);

            Cmat[((size_t)b * QQ + q) * TT + t] = cost;
            s_tile[ql][tl] = cost;
        }
    }
    __syncthreads();

    if (CT != nullptr) {
        #pragma unroll
        for (int k = 0; k < 4; ++k) {
            int tl2 = (tid >> 5) + 8 * k;
            int ql2 = tid & 31;
            int t2 = t0 + tl2, q2 = q0 + ql2;
            if (q2 < QQ && t2 < TT)
                CT[((size_t)b * TT + t2) * QQ + q2] = s_tile[ql2][tl2];
        }
    }

    // fused row-min: per t-row of this tile, min over the tile's q's
    if (tid < 32) {
        int t2 = t0 + tid;
        if (t2 < TT) {
            int qmax = (QQ - q0 < 32) ? (QQ - q0) : 32;
            unsigned long long best = ~0ull;
            for (int ql2 = 0; ql2 < qmax; ++ql2) {
                unsigned ub = __float_as_uint(s_tile[ql2][tid]);
                unsigned mono = (ub & 0x80000000u) ? ~ub : (ub | 0x80000000u);
                unsigned long long key = ((unsigned long long)mono << 10)
                                       | (unsigned)(q0 + ql2);
                if (key < best) best = key;
            }
            atomicMin(&rowkey[(size_t)b * TT + t2], best);
        }
    }
}

// ---------------------------------------------------------------------------
// Kernel C: JV LSA = greedy init (fused raw row mins, v=0) + SAP.
// Round-11 semantics EXACTLY (same keys, same tie-break, same dual math).
// Kept from r12: register v-duals (no LDS v0), 0-based pcol[] owner array
// read per row as one aligned ds_read_b128, hoisted per-row owner tags,
// next-free-row prefetch. REVERTED from r12: speculative 4-candidate row
// prefetch (measured regression: waits on 4 loads instead of 1). After the
// uniform decode of the winner's owner i1, exactly ONE float4 row load.
//   key = mono45(cur) | j:10 | owner:9     (owner = pcol[j-1], frozen/row)
// ---------------------------------------------------------------------------
#define STH 256
#define NW (STH / 64)
#define KCOLS 4
#define MLOW ((1ull << 19) - 1ull)

__device__ __forceinline__ unsigned long long monoKey(double x) {
    unsigned long long ub = (unsigned long long)__double_as_longlong(x);
    return (ub & 0x8000000000000000ull) ? ~ub : (ub | 0x8000000000000000ull);
}
__device__ __forceinline__ double unmonoKey(unsigned long long m) {
    unsigned long long ub = (m >> 63) ? (m & 0x7FFFFFFFFFFFFFFFull) : ~m;
    return __longlong_as_double((long long)ub);
}

__device__ __forceinline__ unsigned wave_min_u32(unsigned x) {
    unsigned t;
    t = (unsigned)__builtin_amdgcn_update_dpp((int)x, (int)x, 0x111, 0xf, 0xf, false); // row_shr:1
    x = (x < t) ? x : t;
    t = (unsigned)__builtin_amdgcn_update_dpp((int)x, (int)x, 0x112, 0xf, 0xf, false); // row_shr:2
    x = (x < t) ? x : t;
    t = (unsigned)__builtin_amdgcn_update_dpp((int)x, (int)x, 0x114, 0xf, 0xf, false); // row_shr:4
    x = (x < t) ? x : t;
    t = (unsigned)__builtin_amdgcn_update_dpp((int)x, (int)x, 0x118, 0xf, 0xf, false); // row_shr:8
    x = (x < t) ? x : t;
    t = (unsigned)__builtin_amdgcn_update_dpp((int)x, (int)x, 0x142, 0xa, 0xf, false); // row_bcast15
    x = (x < t) ? x : t;
    t = (unsigned)__builtin_amdgcn_update_dpp((int)x, (int)x, 0x143, 0xc, 0xf, false); // row_bcast31
    x = (x < t) ? x : t;
    return (unsigned)__builtin_amdgcn_readlane((int)x, 63);
}

__global__ __launch_bounds__(STH)
void lsa_kernel(const float* __restrict__ Mbase,
                long long batchStride, long long rowStride, long long colStride,
                const unsigned long long* __restrict__ rowkey,
                float* __restrict__ outq, float* __restrict__ outt)
{
    const int b = blockIdx.x;
    const float* M = Mbase + (size_t)b * batchStride;
    const int tid = threadIdx.x;

    __shared__ double u0[TT + 1];
    __shared__ __align__(16) int pcol[QQ];     // 0-based column owner (0 = free)
    __shared__ int    way[QQ + 1];
    __shared__ int    claim[QQ + 1];
    __shared__ int    freeRows[TT];
    __shared__ int    usedList[TT + 1];
    __shared__ double Dent[TT + 1];
    __shared__ unsigned long long redK[2][NW];
    __shared__ int    waveBase[NW];
    __shared__ int    chunkBase;

    for (int j = tid; j <= QQ; j += STH) { way[j] = 0; claim[j] = 0x7FFFFFFF; }
    for (int c = tid; c < QQ; c += STH) pcol[c] = 0;
    for (int i = tid + 1; i <= TT; i += STH) {
        unsigned long long rk = rowkey[(size_t)b * TT + i - 1];
        unsigned mono = (unsigned)(rk >> 10);
        unsigned ub = (mono & 0x80000000u) ? (mono & 0x7FFFFFFFu) : ~mono;
        u0[i] = (double)__uint_as_float(ub);     // EXACT row min (float)
    }
    if (tid == 0) chunkBase = 0;
    __syncthreads();

    // ---- greedy: earliest row claims its argmin column.
    for (int i = tid + 1; i <= TT; i += STH)
        atomicMin(&claim[(int)(rowkey[(size_t)b * TT + i - 1] & 1023ull) + 1], i);
    __syncthreads();

    // winners write pcol; losers compacted IN ORDER into freeRows
    for (int r = 0; r < (TT + STH - 1) / STH; ++r) {
        int i = tid + r * STH + 1;
        bool lose = false;
        if (i <= TT) {
            int j = (int)(rowkey[(size_t)b * TT + i - 1] & 1023ull) + 1;
            if (claim[j] == i) pcol[j - 1] = i; else lose = true;
        }
        unsigned long long mk = __ballot(lose);
        int lane = tid & 63, w = tid >> 6;
        int lanePre = __popcll(mk & ((1ull << lane) - 1ull));
        if (lane == 0) waveBase[w] = __popcll(mk);
        __syncthreads();
        if (tid == 0) {
            int acc = chunkBase;
            for (int w2 = 0; w2 < NW; ++w2) { int c = waveBase[w2]; waveBase[w2] = acc; acc += c; }
            chunkBase = acc;
        }
        __syncthreads();
        if (lose) freeRows[waveBase[w] + lanePre] = i;
        __syncthreads();
    }
    const int nFree = chunkBase;

    const int c0 = 4 * tid;                  // first owned column (0-based)
    const bool vec = (colStride == 1) && (c0 < QQ);   // full float4 in range (900%4==0)

    // persistent v duals for owned columns (v starts at 0 everywhere)
    double v0r[KCOLS] = {0.0, 0.0, 0.0, 0.0};
    bool valid[KCOLS];
    #pragma unroll
    for (int k = 0; k < KCOLS; ++k) valid[k] = (c0 + k < QQ);

    // prologue: prefetch first free row
    float4 pre4 = make_float4(0.f, 0.f, 0.f, 0.f);
    if (vec && nFree > 0)
        pre4 = *reinterpret_cast<const float4*>(M + (long long)(freeRows[0] - 1) * rowStride + c0);

    // ---- shortest augmenting path for each unassigned row.
    int par = 0;
    for (int f = 0; f < nFree; ++f) {
        const int i = freeRows[f];

        // per-row constants: owner tags (owner frozen during this Dijkstra)
        unsigned long long tag[KCOLS];
        {
            int own[KCOLS] = {0, 0, 0, 0};
            if (vec) {
                int4 pv = *reinterpret_cast<const int4*>(&pcol[c0]);   // aligned b128
                own[0] = pv.x; own[1] = pv.y; own[2] = pv.z; own[3] = pv.w;
            } else {
                #pragma unroll
                for (int k = 0; k < KCOLS; ++k)
                    if (valid[k]) own[k] = pcol[c0 + k];
            }
            #pragma unroll
            for (int k = 0; k < KCOLS; ++k)
                tag[k] = ((unsigned long long)(c0 + k + 1) << 9)
                       | (unsigned long long)own[k];
        }

        unsigned long long sv[KCOLS];
        #pragma unroll
        for (int k = 0; k < KCOLS; ++k) sv[k] = ~0ull;
        unsigned usedMask = 0;
        int cnt = 1; double D = 0.0; int i0 = i; int j0 = 0; int j1free;
        float4 cur4 = pre4;                      // row i0's data (vec path)

        while (true) {
            float mload[KCOLS];
            if (vec) {
                mload[0] = cur4.x; mload[1] = cur4.y; mload[2] = cur4.z; mload[3] = cur4.w;
            } else {
                const float* Mrow = M + (long long)(i0 - 1) * rowStride;
                #pragma unroll
                for (int k = 0; k < KCOLS; ++k)
                    mload[k] = valid[k] ? Mrow[(long long)(c0 + k) * colStride] : 0.0f;
            }
            const double base = D - u0[i0];

            unsigned long long bk = ~0ull;
            #pragma unroll
            for (int k = 0; k < KCOLS; ++k) {
                if (valid[k] && !((usedMask >> k) & 1u)) {
                    double cur = (double)mload[k] + (base - v0r[k]);
                    unsigned long long key = (monoKey(cur) & ~MLOW) | tag[k];
                    if (key < sv[k]) { sv[k] = key; way[c0 + k + 1] = j0; }
                    if (sv[k] < bk) bk = sv[k];
                }
            }
            // wave-level exact u64 min via two-pass 32-bit DPP
            {
                unsigned hi = (unsigned)(bk >> 32);
                unsigned lo = (unsigned)(bk & 0xFFFFFFFFull);
                unsigned mhi = wave_min_u32(hi);
                unsigned lo2 = (hi == mhi) ? lo : 0xFFFFFFFFu;
                unsigned mlo = wave_min_u32(lo2);
                if ((tid & 63) == 0)
                    redK[par][tid >> 6] = ((unsigned long long)mhi << 32) | mlo;
            }
            __syncthreads();                       // the ONLY per-iteration barrier

            unsigned long long kmin = redK[par][0];
            #pragma unroll
            for (int w = 1; w < NW; ++w) {
                unsigned long long o = redK[par][w];
                if (o < kmin) kmin = o;
            }
            par ^= 1;

            D = unmonoKey(kmin & ~MLOW);
            int j1 = (int)((kmin >> 9) & 1023ull);
            int i1 = (int)(kmin & 511ull);         // owner from the key
            if (i1 == 0) { j1free = j1; break; }   // free column reached

            // exactly ONE row load for the next iteration (winner's owner row)
            if (vec)
                cur4 = *reinterpret_cast<const float4*>(
                    M + (long long)(i1 - 1) * rowStride + c0);

            int cj = j1 - 1;
            if ((cj >> 2) == tid) usedMask |= 1u << (cj & 3);
            if (tid == 0) { usedList[cnt] = j1; Dent[cnt] = D; }
            cnt++;
            j0 = j1; i0 = i1;
        }

        // prefetch next free row's first float4 (hides under the epilogue)
        if (vec && f + 1 < nFree)
            pre4 = *reinterpret_cast<const float4*>(
                M + (long long)(freeRows[f + 1] - 1) * rowStride + c0);

        __syncthreads();   // A: way/usedList/Dent visible, scans done

        // register v-dual updates (all threads, broadcast reads — conflict-free)
        for (int k = 1; k < cnt; ++k) {
            int ju = usedList[k];
            double d = D - Dent[k];
            int rel = ju - 1 - c0;
            if (rel >= 0 && rel < KCOLS) v0r[rel] -= d;
        }
        // u-dual updates (reads PRE-augment pcol; rows distinct)
        for (int k = tid; k < cnt; k += STH) {
            if (k == 0) {
                u0[i] += D;
            } else {
                int ju = usedList[k];
                u0[pcol[ju - 1]] += D - Dent[k];
            }
        }
        __syncthreads();   // B

        if (tid == 0) {
            int jj = j1free;
            while (jj) {
                int jn = way[jj];
                pcol[jj - 1] = (jn == 0) ? i : pcol[jn - 1];
                jj = jn;
            }
        }
        __syncthreads();   // C: augmented pcol visible
    }

    // row2col: pcol[c] > 0 -> target pcol[c]-1 assigned query c
    for (int c = tid; c < QQ; c += STH) {
        int pi = pcol[c];
        if (pi > 0) outq[(size_t)b * TT + (pi - 1)] = (float)c;
    }
    for (int t = tid; t < TT; t += STH)
        outt[(size_t)b * TT + t] = (float)t;
}

// ---------------------------------------------------------------------------
extern "C" void kernel_launch(void* const* d_in, const int* in_sizes, int n_in,
                              void* d_out, int out_size, void* d_ws, size_t ws_size,
                              hipStream_t stream)
{
    const float* logits  = (const float*)d_in[0];
    const float* pboxes  = (const float*)d_in[1];
    const float* pcut    = (const float*)d_in[2];
    const int*   tlabels = (const int*)d_in[3];
    const float* tboxes  = (const float*)d_in[4];
    const float* tcut    = (const float*)d_in[5];

    float* out  = (float*)d_out;
    float* Cmat = out;                                   // B*Q*T
    float* outq = out + (size_t)BB * QQ * TT;            // B*T
    float* outt = outq + (size_t)BB * TT;                // B*T

    const size_t statsBytes = (size_t)BB * QQ * sizeof(float2);              // 230,400
    const size_t rkBytes    = (size_t)BB * TT * sizeof(unsigned long long);  // 76,800
    const size_t ctBytes    = (size_t)BB * TT * QQ * sizeof(float);          // 34.56 MB

    float2* stats = (float2*)d_ws;
    unsigned long long* rowkey = (unsigned long long*)((char*)d_ws + statsBytes);
    char*   ctPtr = (char*)d_ws + statsBytes + rkBytes;
    bool haveCT = (ws_size >= statsBytes + rkBytes + ctBytes);
    float* CT = haveCT ? (float*)ctPtr : nullptr;

    hipMemsetAsync(rowkey, 0xFF, rkBytes, stream);

    softmax_stats_kernel<<<BB * QQ, 256, 0, stream>>>(logits, stats);

    dim3 grid((QQ + 31) / 32, (TT + 31) / 32, BB);
    cost_kernel<<<grid, 256, 0, stream>>>(logits, pboxes, pcut, tlabels, tboxes,
                                          tcut, stats, Cmat, CT, rowkey);

    if (haveCT) {
        lsa_kernel<<<BB, STH, 0, stream>>>(
            CT, (long long)TT * QQ, (long long)QQ, 1LL, rowkey, outq, outt);
    } else {
        lsa_kernel<<<BB, STH, 0, stream>>>(
            Cmat, (long long)QQ * TT, 1LL, (long long)TT, rowkey, outq, outt);
    }
}

// Round 14
// 262.798 us; speedup vs baseline: 1.0689x; 1.0172x over previous
//
#include <hip/hip_runtime.h>
#include <float.h>

#define BB 32
#define QQ 900
#define TT 300
#define CC 256

// ---------------------------------------------------------------------------
// Kernel A: per-(b,q) softmax stats: rowmax and sum(exp(l - max)).
// Block 0 additionally initializes the rowkey array (replaces a separate
// hipMemsetAsync dispatch; stream order guarantees completion before
// cost_kernel's atomicMin operations).
// ---------------------------------------------------------------------------
__global__ __launch_bounds__(256)
void softmax_stats_kernel(const float* __restrict__ logits, float2* __restrict__ stats,
                          unsigned long long* __restrict__ rowkey)
{
    const int row = blockIdx.x;                 // b*QQ + q
    const float* L = logits + (size_t)row * CC;
    const int tid = threadIdx.x;

    if (row == 0) {
        for (int k = tid; k < BB * TT; k += 256) rowkey[k] = ~0ull;
    }

    float x = L[tid];

    __shared__ float sredm[4];
    __shared__ float sreds[4];

    float m = x;
    #pragma unroll
    for (int off = 32; off > 0; off >>= 1)
        m = fmaxf(m, __shfl_down(m, off, 64));
    if ((tid & 63) == 0) sredm[tid >> 6] = m;
    __syncthreads();
    m = fmaxf(fmaxf(sredm[0], sredm[1]), fmaxf(sredm[2], sredm[3]));

    float s = expf(x - m);
    #pragma unroll
    for (int off = 32; off > 0; off >>= 1)
        s += __shfl_down(s, off, 64);
    if ((tid & 63) == 0) sreds[tid >> 6] = s;
    __syncthreads();
    if (tid == 0)
        stats[row] = make_float2(m, sreds[0] + sreds[1] + sreds[2] + sreds[3]);
}

// ---------------------------------------------------------------------------
// Kernel B: cost matrix, 32q x 32t tiles. Writes Cmat [b][q][t] coalesced,
// CT [b][t][q] coalesced (LDS transpose), and the per-(b,t) row-min key via
// one u64 atomicMin per (tile, t): key = mono32(cost)<<10 | q.
// ---------------------------------------------------------------------------
__global__ __launch_bounds__(256)
void cost_kernel(const float* __restrict__ logits,
                 const float* __restrict__ pboxes,
                 const float* __restrict__ pcut,
                 const int*   __restrict__ tlabels,
                 const float* __restrict__ tboxes,
                 const float* __restrict__ tcut,
                 const float2* __restrict__ stats,
                 float* __restrict__ Cmat,
                 float* __restrict__ CT,
                 unsigned long long* __restrict__ rowkey)
{
    const int b  = blockIdx.z;
    const int q0 = blockIdx.x * 32;
    const int t0 = blockIdx.y * 32;
    const int tid = threadIdx.x;

    __shared__ float s_pb[32][4], s_tb[32][4];
    __shared__ float s_pc[32], s_tc[32], s_pm[32], s_ps[32], s_pa[32], s_ta[32];
    __shared__ int   s_tl[32];
    __shared__ float s_tile[32][33];

    if (tid < 32) {
        int q = q0 + tid;
        if (q < QQ) {
            const float* pb = pboxes + ((size_t)b * QQ + q) * 4;
            float x1 = pb[0], y1 = pb[1], x2 = pb[2], y2 = pb[3];
            s_pb[tid][0] = x1; s_pb[tid][1] = y1; s_pb[tid][2] = x2; s_pb[tid][3] = y2;
            s_pa[tid] = (x2 - x1) * (y2 - y1);
            s_pc[tid] = pcut[(size_t)b * QQ + q];
            float2 st = stats[(size_t)b * QQ + q];
            s_pm[tid] = st.x; s_ps[tid] = st.y;
        }
    } else if (tid < 64) {
        int tl = tid - 32;
        int t = t0 + tl;
        if (t < TT) {
            const float* tb = tboxes + ((size_t)b * TT + t) * 4;
            float x1 = tb[0], y1 = tb[1], x2 = tb[2], y2 = tb[3];
            s_tb[tl][0] = x1; s_tb[tl][1] = y1; s_tb[tl][2] = x2; s_tb[tl][3] = y2;
            s_ta[tl] = (x2 - x1) * (y2 - y1);
            s_tc[tl] = tcut[(size_t)b * TT + t];
            s_tl[tl] = tlabels[(size_t)b * TT + t];
        }
    }
    __syncthreads();

    const int tl = tid & 31;
    const int t  = t0 + tl;
    #pragma unroll
    for (int k = 0; k < 4; ++k) {
        int ql = (tid >> 5) + 8 * k;
        int q  = q0 + ql;
        if (q < QQ && t < TT) {
            float lg = logits[((size_t)b * QQ + q) * CC + s_tl[tl]];
            float cclass = -(expf(lg - s_pm[ql]) / s_ps[ql]);

            float px1 = s_pb[ql][0], py1 = s_pb[ql][1], px2 = s_pb[ql][2], py2 = s_pb[ql][3];
            float tx1 = s_tb[tl][0], ty1 = s_tb[tl][1], tx2 = s_tb[tl][2], ty2 = s_tb[tl][3];

            float l1 = fabsf(px1 - tx1) + fabsf(py1 - ty1) + fabsf(px2 - tx2) + fabsf(py2 - ty2);

            float iw = fmaxf(fminf(px2, tx2) - fmaxf(px1, tx1), 0.0f);
            float ih = fmaxf(fminf(py2, ty2) - fmaxf(py1, ty1), 0.0f);
            float inter = iw * ih;
            float uni = s_pa[ql] + s_ta[tl] - inter;
            float iou = inter / uni;

            float ew = fmaxf(fmaxf(px2, tx2) - fminf(px1, tx1), 0.0f);
            float eh = fmaxf(fmaxf(py2, ty2) - fminf(py1, ty1), 0.0f);
            float enc = ew * eh;
            float giou = iou - (enc - uni) / enc;

            float cost = 5.0f * l1 + cclass - 2.0f * giou
                       + 2.0f * fabsf(s_pc[ql] - s_tc[tl]);

            Cmat[((size_t)b * QQ + q) * TT + t] = cost;
            s_tile[ql][tl] = cost;
        }
    }
    __syncthreads();

    if (CT != nullptr) {
        #pragma unroll
        for (int k = 0; k < 4; ++k) {
            int tl2 = (tid >> 5) + 8 * k;
            int ql2 = tid & 31;
            int t2 = t0 + tl2, q2 = q0 + ql2;
            if (q2 < QQ && t2 < TT)
                CT[((size_t)b * TT + t2) * QQ + q2] = s_tile[ql2][tl2];
        }
    }

    // fused row-min: per t-row of this tile, min over the tile's q's
    if (tid < 32) {
        int t2 = t0 + tid;
        if (t2 < TT) {
            int qmax = (QQ - q0 < 32) ? (QQ - q0) : 32;
            unsigned long long best = ~0ull;
            for (int ql2 = 0; ql2 < qmax; ++ql2) {
                unsigned ub = __float_as_uint(s_tile[ql2][tid]);
                unsigned mono = (ub & 0x80000000u) ? ~ub : (ub | 0x80000000u);
                unsigned long long key = ((unsigned long long)mono << 10)
                                       | (unsigned)(q0 + ql2);
                if (key < best) best = key;
            }
            atomicMin(&rowkey[(size_t)b * TT + t2], best);
        }
    }
}

// ---------------------------------------------------------------------------
// Kernel C: JV LSA = greedy init (fused raw row mins, v=0) + SAP.
// Validated round-13 structure, byte-identical semantics:
// register v-duals, 0-based pcol[] owner array (aligned b128 per-row read),
// hoisted per-row owner tags, next-free-row prefetch, exactly ONE float4 row
// load per Dijkstra iteration after the uniform winner decode.
//   key = mono45(cur) | j:10 | owner:9     (owner = pcol[j-1], frozen/row)
// Wave u64 argmin via two-pass 32-bit DPP min (exact lexicographic).
// ---------------------------------------------------------------------------
#define STH 256
#define NW (STH / 64)
#define KCOLS 4
#define MLOW ((1ull << 19) - 1ull)

__device__ __forceinline__ unsigned long long monoKey(double x) {
    unsigned long long ub = (unsigned long long)__double_as_longlong(x);
    return (ub & 0x8000000000000000ull) ? ~ub : (ub | 0x8000000000000000ull);
}
__device__ __forceinline__ double unmonoKey(unsigned long long m) {
    unsigned long long ub = (m >> 63) ? (m & 0x7FFFFFFFFFFFFFFFull) : ~m;
    return __longlong_as_double((long long)ub);
}

__device__ __forceinline__ unsigned wave_min_u32(unsigned x) {
    unsigned t;
    t = (unsigned)__builtin_amdgcn_update_dpp((int)x, (int)x, 0x111, 0xf, 0xf, false); // row_shr:1
    x = (x < t) ? x : t;
    t = (unsigned)__builtin_amdgcn_update_dpp((int)x, (int)x, 0x112, 0xf, 0xf, false); // row_shr:2
    x = (x < t) ? x : t;
    t = (unsigned)__builtin_amdgcn_update_dpp((int)x, (int)x, 0x114, 0xf, 0xf, false); // row_shr:4
    x = (x < t) ? x : t;
    t = (unsigned)__builtin_amdgcn_update_dpp((int)x, (int)x, 0x118, 0xf, 0xf, false); // row_shr:8
    x = (x < t) ? x : t;
    t = (unsigned)__builtin_amdgcn_update_dpp((int)x, (int)x, 0x142, 0xa, 0xf, false); // row_bcast15
    x = (x < t) ? x : t;
    t = (unsigned)__builtin_amdgcn_update_dpp((int)x, (int)x, 0x143, 0xc, 0xf, false); // row_bcast31
    x = (x < t) ? x : t;
    return (unsigned)__builtin_amdgcn_readlane((int)x, 63);
}

__global__ __launch_bounds__(STH)
void lsa_kernel(const float* __restrict__ Mbase,
                long long batchStride, long long rowStride, long long colStride,
                const unsigned long long* __restrict__ rowkey,
                float* __restrict__ outq, float* __restrict__ outt)
{
    const int b = blockIdx.x;
    const float* M = Mbase + (size_t)b * batchStride;
    const int tid = threadIdx.x;

    __shared__ double u0[TT + 1];
    __shared__ __align__(16) int pcol[QQ];     // 0-based column owner (0 = free)
    __shared__ int    way[QQ + 1];
    __shared__ int    claim[QQ + 1];
    __shared__ int    freeRows[TT];
    __shared__ int    usedList[TT + 1];
    __shared__ double Dent[TT + 1];
    __shared__ unsigned long long redK[2][NW];
    __shared__ int    waveBase[NW];
    __shared__ int    chunkBase;

    for (int j = tid; j <= QQ; j += STH) { way[j] = 0; claim[j] = 0x7FFFFFFF; }
    for (int c = tid; c < QQ; c += STH) pcol[c] = 0;
    for (int i = tid + 1; i <= TT; i += STH) {
        unsigned long long rk = rowkey[(size_t)b * TT + i - 1];
        unsigned mono = (unsigned)(rk >> 10);
        unsigned ub = (mono & 0x80000000u) ? (mono & 0x7FFFFFFFu) : ~mono;
        u0[i] = (double)__uint_as_float(ub);     // EXACT row min (float)
    }
    if (tid == 0) chunkBase = 0;
    __syncthreads();

    // ---- greedy: earliest row claims its argmin column.
    for (int i = tid + 1; i <= TT; i += STH)
        atomicMin(&claim[(int)(rowkey[(size_t)b * TT + i - 1] & 1023ull) + 1], i);
    __syncthreads();

    // winners write pcol; losers compacted IN ORDER into freeRows
    for (int r = 0; r < (TT + STH - 1) / STH; ++r) {
        int i = tid + r * STH + 1;
        bool lose = false;
        if (i <= TT) {
            int j = (int)(rowkey[(size_t)b * TT + i - 1] & 1023ull) + 1;
            if (claim[j] == i) pcol[j - 1] = i; else lose = true;
        }
        unsigned long long mk = __ballot(lose);
        int lane = tid & 63, w = tid >> 6;
        int lanePre = __popcll(mk & ((1ull << lane) - 1ull));
        if (lane == 0) waveBase[w] = __popcll(mk);
        __syncthreads();
        if (tid == 0) {
            int acc = chunkBase;
            for (int w2 = 0; w2 < NW; ++w2) { int c = waveBase[w2]; waveBase[w2] = acc; acc += c; }
            chunkBase = acc;
        }
        __syncthreads();
        if (lose) freeRows[waveBase[w] + lanePre] = i;
        __syncthreads();
    }
    const int nFree = chunkBase;

    const int c0 = 4 * tid;                  // first owned column (0-based)
    const bool vec = (colStride == 1) && (c0 < QQ);   // full float4 in range (900%4==0)

    // persistent v duals for owned columns (v starts at 0 everywhere)
    double v0r[KCOLS] = {0.0, 0.0, 0.0, 0.0};
    bool valid[KCOLS];
    #pragma unroll
    for (int k = 0; k < KCOLS; ++k) valid[k] = (c0 + k < QQ);

    // prologue: prefetch first free row
    float4 pre4 = make_float4(0.f, 0.f, 0.f, 0.f);
    if (vec && nFree > 0)
        pre4 = *reinterpret_cast<const float4*>(M + (long long)(freeRows[0] - 1) * rowStride + c0);

    // ---- shortest augmenting path for each unassigned row.
    int par = 0;
    for (int f = 0; f < nFree; ++f) {
        const int i = freeRows[f];

        // per-row constants: owner tags (owner frozen during this Dijkstra)
        unsigned long long tag[KCOLS];
        {
            int own[KCOLS] = {0, 0, 0, 0};
            if (vec) {
                int4 pv = *reinterpret_cast<const int4*>(&pcol[c0]);   // aligned b128
                own[0] = pv.x; own[1] = pv.y; own[2] = pv.z; own[3] = pv.w;
            } else {
                #pragma unroll
                for (int k = 0; k < KCOLS; ++k)
                    if (valid[k]) own[k] = pcol[c0 + k];
            }
            #pragma unroll
            for (int k = 0; k < KCOLS; ++k)
                tag[k] = ((unsigned long long)(c0 + k + 1) << 9)
                       | (unsigned long long)own[k];
        }

        unsigned long long sv[KCOLS];
        #pragma unroll
        for (int k = 0; k < KCOLS; ++k) sv[k] = ~0ull;
        unsigned usedMask = 0;
        int cnt = 1; double D = 0.0; int i0 = i; int j0 = 0; int j1free;
        float4 cur4 = pre4;                      // row i0's data (vec path)

        while (true) {
            float mload[KCOLS];
            if (vec) {
                mload[0] = cur4.x; mload[1] = cur4.y; mload[2] = cur4.z; mload[3] = cur4.w;
            } else {
                const float* Mrow = M + (long long)(i0 - 1) * rowStride;
                #pragma unroll
                for (int k = 0; k < KCOLS; ++k)
                    mload[k] = valid[k] ? Mrow[(long long)(c0 + k) * colStride] : 0.0f;
            }
            const double base = D - u0[i0];

            unsigned long long bk = ~0ull;
            #pragma unroll
            for (int k = 0; k < KCOLS; ++k) {
                if (valid[k] && !((usedMask >> k) & 1u)) {
                    double cur = (double)mload[k] + (base - v0r[k]);
                    unsigned long long key = (monoKey(cur) & ~MLOW) | tag[k];
                    if (key < sv[k]) { sv[k] = key; way[c0 + k + 1] = j0; }
                    if (sv[k] < bk) bk = sv[k];
                }
            }
            // wave-level exact u64 min via two-pass 32-bit DPP
            {
                unsigned hi = (unsigned)(bk >> 32);
                unsigned lo = (unsigned)(bk & 0xFFFFFFFFull);
                unsigned mhi = wave_min_u32(hi);
                unsigned lo2 = (hi == mhi) ? lo : 0xFFFFFFFFu;
                unsigned mlo = wave_min_u32(lo2);
                if ((tid & 63) == 0)
                    redK[par][tid >> 6] = ((unsigned long long)mhi << 32) | mlo;
            }
            __syncthreads();                       // the ONLY per-iteration barrier

            unsigned long long kmin = redK[par][0];
            #pragma unroll
            for (int w = 1; w < NW; ++w) {
                unsigned long long o = redK[par][w];
                if (o < kmin) kmin = o;
            }
            par ^= 1;

            D = unmonoKey(kmin & ~MLOW);
            int j1 = (int)((kmin >> 9) & 1023ull);
            int i1 = (int)(kmin & 511ull);         // owner from the key
            if (i1 == 0) { j1free = j1; break; }   // free column reached

            // exactly ONE row load for the next iteration (winner's owner row)
            if (vec)
                cur4 = *reinterpret_cast<const float4*>(
                    M + (long long)(i1 - 1) * rowStride + c0);

            int cj = j1 - 1;
            if ((cj >> 2) == tid) usedMask |= 1u << (cj & 3);
            if (tid == 0) { usedList[cnt] = j1; Dent[cnt] = D; }
            cnt++;
            j0 = j1; i0 = i1;
        }

        // prefetch next free row's first float4 (hides under the epilogue)
        if (vec && f + 1 < nFree)
            pre4 = *reinterpret_cast<const float4*>(
                M + (long long)(freeRows[f + 1] - 1) * rowStride + c0);

        __syncthreads();   // A: way/usedList/Dent visible, scans done

        // register v-dual updates (all threads, broadcast reads — conflict-free)
        for (int k = 1; k < cnt; ++k) {
            int ju = usedList[k];
            double d = D - Dent[k];
            int rel = ju - 1 - c0;
            if (rel >= 0 && rel < KCOLS) v0r[rel] -= d;
        }
        // u-dual updates (reads PRE-augment pcol; rows distinct)
        for (int k = tid; k < cnt; k += STH) {
            if (k == 0) {
                u0[i] += D;
            } else {
                int ju = usedList[k];
                u0[pcol[ju - 1]] += D - Dent[k];
            }
        }
        __syncthreads();   // B

        if (tid == 0) {
            int jj = j1free;
            while (jj) {
                int jn = way[jj];
                pcol[jj - 1] = (jn == 0) ? i : pcol[jn - 1];
                jj = jn;
            }
        }
        __syncthreads();   // C: augmented pcol visible
    }

    // row2col: pcol[c] > 0 -> target pcol[c]-1 assigned query c
    for (int c = tid; c < QQ; c += STH) {
        int pi = pcol[c];
        if (pi > 0) outq[(size_t)b * TT + (pi - 1)] = (float)c;
    }
    for (int t = tid; t < TT; t += STH)
        outt[(size_t)b * TT + t] = (float)t;
}

// ---------------------------------------------------------------------------
extern "C" void kernel_launch(void* const* d_in, const int* in_sizes, int n_in,
                              void* d_out, int out_size, void* d_ws, size_t ws_size,
                              hipStream_t stream)
{
    const float* logits  = (const float*)d_in[0];
    const float* pboxes  = (const float*)d_in[1];
    const float* pcut    = (const float*)d_in[2];
    const int*   tlabels = (const int*)d_in[3];
    const float* tboxes  = (const float*)d_in[4];
    const float* tcut    = (const float*)d_in[5];

    float* out  = (float*)d_out;
    float* Cmat = out;                                   // B*Q*T
    float* outq = out + (size_t)BB * QQ * TT;            // B*T
    float* outt = outq + (size_t)BB * TT;                // B*T

    const size_t statsBytes = (size_t)BB * QQ * sizeof(float2);              // 230,400
    const size_t rkBytes    = (size_t)BB * TT * sizeof(unsigned long long);  // 76,800
    const size_t ctBytes    = (size_t)BB * TT * QQ * sizeof(float);          // 34.56 MB

    float2* stats = (float2*)d_ws;
    unsigned long long* rowkey = (unsigned long long*)((char*)d_ws + statsBytes);
    char*   ctPtr = (char*)d_ws + statsBytes + rkBytes;
    bool haveCT = (ws_size >= statsBytes + rkBytes + ctBytes);
    float* CT = haveCT ? (float*)ctPtr : nullptr;

    softmax_stats_kernel<<<BB * QQ, 256, 0, stream>>>(logits, stats, rowkey);

    dim3 grid((QQ + 31) / 32, (TT + 31) / 32, BB);
    cost_kernel<<<grid, 256, 0, stream>>>(logits, pboxes, pcut, tlabels, tboxes,
                                          tcut, stats, Cmat, CT, rowkey);

    if (haveCT) {
        lsa_kernel<<<BB, STH, 0, stream>>>(
            CT, (long long)TT * QQ, (long long)QQ, 1LL, rowkey, outq, outt);
    } else {
        lsa_kernel<<<BB, STH, 0, stream>>>(
            Cmat, (long long)QQ * TT, 1LL, (long long)TT, rowkey, outq, outt);
    }
}